// Round 12
// baseline (292.063 us; speedup 1.0000x reference)
//
// AttentionModel: fused QKV projection + causal softmax attention, MI355X/gfx950.
// Round 15: the wave-staging model. Fit across R8/R9/R12/R14: staging runs at
// ~2.75 GB/s PER RESIDENT WAVE (8KB outstanding / 2.9us latency); kernel time
// = staged_bytes / (2.75GB/s x resident_waves). Explains R8 (4w: 11GB/s/CU),
// R9 proj (12w: 69us pred vs 68 meas), R12-vs-R14 scores null (16w == 18w).
// Moves this round (merit = bytes/waves):
//  - proj: V-transpose LDS union 66KB->48KB (two-pass [128][132] tile) +
//    launch_bounds(256,3) -> 3 blocks/CU = 12 staging waves (was 8), grid 768
//    = exactly 1.0 residency round (zero tail). 393MB/8.4TB/s ~= 47us.
//  - pv: grid-capped at 2 blocks/CU since R9 -> split dt 4->8 (64-col slices):
//    1024 blocks, 24KB LDS, acc[4][2], (256,4) -> 4 blocks/CU, ALL resident.
//    Bytes 278->417MB but waves 8->16: ~36us. QTMAP makes each CU's 4
//    co-resident blocks {qi,qi+4,qi+8,qi+12} sum to identical K-work.
//  - scores (R14 8-wave 256x128) / softmax / cvtw unchanged.
// ws layout (bytes): P 0..64M | Qb 64M | Kb 80M | Vt 112M | Wf16 128M

#include <hip/hip_runtime.h>
#include <stdint.h>
#include <stddef.h>
#include <math.h>

typedef _Float16 half8 __attribute__((ext_vector_type(8)));
typedef float f32x4 __attribute__((ext_vector_type(4)));

#define SCALE_QK 0.04419417382415922f  // 1/sqrt(512)

__device__ __forceinline__ void gload16(const void* g, void* lds) {
  __builtin_amdgcn_global_load_lds(
      (const __attribute__((address_space(1))) void*)g,
      (__attribute__((address_space(3))) void*)lds,
      16, 0, 0);
}

// ---- wide K-loop (proj): C[128x256] = A[128xK](fp32) * B^T, BK=64, single-buf.
// LDS contract (proven zero-conflict): element (row r, 8-group g) at halfword
// r*64 + (g^(r&7))*8. 4 waves as 2(m) x 2(n); wave tile 64x128 -> acc[4][8].
__device__ __forceinline__ void run_kloop_wide(const float* Arow0, const _Float16* Brow0,
                                               int lda, int ldb, int kIters,
                                               _Float16* As, _Float16* Bs,
                                               f32x4 (&acc)[4][8])
{
  const int tid  = threadIdx.x;
  const int lane = tid & 63;
  const int w    = tid >> 6;
  const int wm   = w >> 1, wn = w & 1;
  const int srow = tid >> 3;          // staging row within 32-row chunk
  const int sg   = tid & 7;           // staging 8-elem group slot
  const int swz  = sg ^ (srow & 7);   // swizzled group (source side)
  const int fr   = lane & 15;
  const int fq   = lane >> 4;
  const int fx   = lane & 7;

  for (int it = 0; it < kIters; ++it) {
    const int k0 = it * 64;
    f32x4 preF[8];
    #pragma unroll
    for (int i = 0; i < 4; ++i) {
      const float* src = Arow0 + (size_t)(i*32 + srow) * lda + (k0 + sg*8);
      preF[2*i]   = *(const f32x4*)src;
      preF[2*i+1] = *(const f32x4*)(src + 4);
    }
    #pragma unroll
    for (int i = 0; i < 8; ++i)   // B: 256 rows
      gload16(Brow0 + (size_t)(i*32 + srow) * ldb + (k0 + swz*8), Bs + i*2048 + w*512);
    #pragma unroll
    for (int i = 0; i < 4; ++i) {
      f32x4 x = preF[2*i], y = preF[2*i+1];
      half8 h;
      h[0]=(_Float16)x[0]; h[1]=(_Float16)x[1]; h[2]=(_Float16)x[2]; h[3]=(_Float16)x[3];
      h[4]=(_Float16)y[0]; h[5]=(_Float16)y[1]; h[6]=(_Float16)y[2]; h[7]=(_Float16)y[3];
      *(half8*)(As + (i*32 + srow)*64 + swz*8) = h;
    }
    __syncthreads();

    #pragma unroll
    for (int ks = 0; ks < 2; ++ks) {
      half8 av[4], bv[8];
      const int slot = (ks*4 + fq) ^ fx;
      #pragma unroll
      for (int i = 0; i < 4; ++i)
        av[i] = *(const half8*)(As + (wm*64 + i*16 + fr)*64 + slot*8);
      #pragma unroll
      for (int j = 0; j < 8; ++j)
        bv[j] = *(const half8*)(Bs + (wn*128 + j*16 + fr)*64 + slot*8);
      #pragma unroll
      for (int i = 0; i < 4; ++i) {
        #pragma unroll
        for (int j = 0; j < 8; ++j)
          acc[i][j] = __builtin_amdgcn_mfma_f32_16x16x32_f16(av[i], bv[j], acc[i][j], 0, 0, 0);
      }
    }
    __syncthreads();
  }
}

// ---- weights fp32 -> f16 (3 x 512x512 concatenated) ----
__global__ __launch_bounds__(256) void k_cvtw(const float* __restrict__ Wq,
                                              const float* __restrict__ Wk,
                                              const float* __restrict__ Wv,
                                              _Float16* __restrict__ Wb)
{
  const int t = blockIdx.x * 256 + threadIdx.x;
  const int base = t * 8;
  const int z = base >> 18;
  const int off = base & 262143;
  const float* src = (z == 0) ? Wq : ((z == 1) ? Wk : Wv);
  f32x4 a = *(const f32x4*)(src + off);
  f32x4 b = *(const f32x4*)(src + off + 4);
  half8 h;
  h[0]=(_Float16)a[0]; h[1]=(_Float16)a[1]; h[2]=(_Float16)a[2]; h[3]=(_Float16)a[3];
  h[4]=(_Float16)b[0]; h[5]=(_Float16)b[1]; h[6]=(_Float16)b[2]; h[7]=(_Float16)b[3];
  *(half8*)(Wb + base) = h;
}

// ---- projections: X[16384x512](fp32) @ W^T + bias -> f16; V direct-transposed ----
// 1D grid 768: xcd = bid%8; i = bid/8 (0..95); p = xcd*48 + i/2; nt2 = i%2;
// z = p/128, mt = p%128. Block output 128 x 256 (cols nt2*256..+256).
// Q output (z==0) is PRE-SCALED by 1/sqrt(512) (bias included).
// LDS 48KB (V-transpose done in two 128-col passes) -> 3 blocks/CU, grid = 1.0
// residency round, 12 staging waves/CU.
__global__ __launch_bounds__(256, 3) void k_proj(const float* __restrict__ q,
                                                 const float* __restrict__ k,
                                                 const float* __restrict__ v,
                                                 const _Float16* __restrict__ Wb,
                                                 const float* __restrict__ bq,
                                                 const float* __restrict__ bk,
                                                 const float* __restrict__ bv,
                                                 _Float16* __restrict__ Qb,
                                                 _Float16* __restrict__ Kb,
                                                 _Float16* __restrict__ Vt)
{
  // union: {As 8192 + Bs 16384 halfs = 48KB} / V-transpose pass tile [128][132] (33.8KB)
  __shared__ __align__(16) _Float16 LDSbuf[24576];
  _Float16* As = LDSbuf;
  _Float16* Bs = LDSbuf + 8192;

  const int bid = blockIdx.x;
  const int xcd = bid & 7, i = bid >> 3;
  const int p = xcd * 48 + (i >> 1);
  const int nt2 = i & 1;
  const int z = p >> 7, mt = p & 127;

  const float* A     = (z == 0) ? q  : (z == 1) ? k  : v;
  const float* bia   = (z == 0) ? bq : (z == 1) ? bk : bv;
  const _Float16* B  = Wb + (size_t)z * 512 * 512;

  f32x4 acc[4][8] = {};
  run_kloop_wide(A + (size_t)mt*128*512, B + (size_t)nt2*256*512, 512, 512, 8,
                 As, Bs, acc);

  const int tid = threadIdx.x;
  const int lane = tid & 63, w = tid >> 6;
  const int wm = w >> 1, wn = w & 1;
  const int fr = lane & 15, fq = lane >> 4;   // C/D: col=lane&15, row=(lane>>4)*4+reg

  if (z < 2) {
    _Float16* C = (z == 0) ? Qb : Kb;
    const float osc = (z == 0) ? SCALE_QK : 1.0f;   // pre-scale Q (and its bias)
    #pragma unroll
    for (int j = 0; j < 8; ++j) {
      const int col = nt2*256 + wn*128 + j*16 + fr;
      const float bval = bia[col];
      #pragma unroll
      for (int i2 = 0; i2 < 4; ++i2) {
        const int row = mt*128 + wm*64 + i2*16 + fq*4;
        #pragma unroll
        for (int r = 0; r < 4; ++r)
          C[(size_t)(row + r) * 512 + col] = (_Float16)((acc[i2][j][r] + bval) * osc);
      }
    }
  } else {
    // V: two 128-col passes through a [128][132] transposed LDS tile.
    // Pass h: waves with wn==h write their cols (d-local = j*16+fr, 0..127),
    // then ALL threads copy those 128 d-rows to Vt coalesced.
    _Float16* sm = LDSbuf;   // kloop ended with syncthreads: LDS free
    const int bb = mt >> 4, s0 = (mt & 15) * 128;
    #pragma unroll
    for (int h = 0; h < 2; ++h) {
      if (wn == h) {
        #pragma unroll
        for (int j = 0; j < 8; ++j) {
          const int dl = j*16 + fr;                   // 0..127 (d within pass)
          const float bval = bia[nt2*256 + h*128 + dl];
          #pragma unroll
          for (int i2 = 0; i2 < 4; ++i2) {
            const int rowloc = wm*64 + i2*16 + fq*4;  // 0..127 (s within tile)
            #pragma unroll
            for (int r = 0; r < 4; ++r)
              sm[dl*132 + rowloc + r] = (_Float16)(acc[i2][j][r] + bval);
          }
        }
      }
      __syncthreads();
      #pragma unroll
      for (int q8 = 0; q8 < 8; ++q8) {
        const int dloc = q8*16 + (tid >> 4);          // 0..127
        const int ch   = tid & 15;
        half8 o = *(const half8*)&sm[dloc*132 + ch*8];
        *(half8*)(Vt + ((size_t)bb*512 + nt2*256 + h*128 + dloc)*2048 + s0 + ch*8) = o;
      }
      if (h == 0) __syncthreads();   // writers of pass 1 wait for readers of pass 0
    }
  }
}

// ---- scores: S = (Q*scale) K^T, 8-wave 256x128 tile (R14) ----
// grid 576, 512 threads: b = bid%8 (-> XCD b); t = 71 - bid/8 (heavy-first)
// decoded to (qp, kt), kt in [0, 2qp+2). Waves 4(m) x 2(n), wave tile 64x64.
__global__ __launch_bounds__(512, 4) void k_scores(const _Float16* __restrict__ Qb,
                                                   const _Float16* __restrict__ Kb,
                                                   _Float16* __restrict__ P)
{
  __shared__ __align__(16) _Float16 As[256*64], Bs[128*64];   // 48 KB
  const int bid = blockIdx.x;
  const int b = bid & 7;
  const int t = 71 - (bid >> 3);
  int qp = 0, accum = 0;
  while (accum + 2*qp + 2 <= t) { accum += 2*qp + 2; ++qp; }
  const int kt = t - accum;          // 0 .. 2qp+1
  const int qt0 = 2 * qp;

  const int tid  = threadIdx.x;
  const int lane = tid & 63;
  const int w    = tid >> 6;         // 0..7
  const int wm   = w >> 1, wn = w & 1;
  const int srow = tid >> 3;         // 0..63 (staging row within 64-row chunk)
  const int sg   = tid & 7;
  const int swz  = sg ^ (srow & 7);
  const int fr   = lane & 15;
  const int fq   = lane >> 4;
  const int fx   = lane & 7;

  const _Float16* Aq = Qb + ((size_t)b*2048 + (size_t)qt0*128)*512;
  const _Float16* Bk = Kb + ((size_t)b*2048 + (size_t)kt*128)*512;

  f32x4 acc[4][4] = {};
  for (int it = 0; it < 8; ++it) {
    const int k0 = it * 64;
    #pragma unroll
    for (int i = 0; i < 4; ++i)   // A: 256 rows (4 x 64-row passes)
      gload16(Aq + (size_t)(i*64 + srow) * 512 + (k0 + swz*8), As + i*4096 + w*512);
    #pragma unroll
    for (int i = 0; i < 2; ++i)   // B: 128 rows (2 x 64-row passes)
      gload16(Bk + (size_t)(i*64 + srow) * 512 + (k0 + swz*8), Bs + i*4096 + w*512);
    __syncthreads();

    #pragma unroll
    for (int ks = 0; ks < 2; ++ks) {
      half8 av[4], bv[4];
      const int slot = (ks*4 + fq) ^ fx;
      #pragma unroll
      for (int i = 0; i < 4; ++i) {
        av[i] = *(const half8*)(As + (wm*64 + i*16 + fr)*64 + slot*8);
        bv[i] = *(const half8*)(Bs + (wn*64 + i*16 + fr)*64 + slot*8);
      }
      #pragma unroll
      for (int i = 0; i < 4; ++i) {
        #pragma unroll
        for (int j = 0; j < 4; ++j)
          acc[i][j] = __builtin_amdgcn_mfma_f32_16x16x32_f16(av[i], bv[j], acc[i][j], 0, 0, 0);
      }
    }
    __syncthreads();
  }

  // epilogue: wave's rows live in qt tile qt0 + (wm>>1)
  const int qt = qt0 + (wm >> 1);
  if (kt <= qt) {
    const bool diag = (kt == qt);
    #pragma unroll
    for (int i = 0; i < 4; ++i) {
      const int rl = (wm & 1)*64 + i*16 + fq*4;      // row within the qt tile
      #pragma unroll
      for (int j = 0; j < 4; ++j) {
        const int cl = wn*64 + j*16 + fr;            // col within kt tile
        #pragma unroll
        for (int r = 0; r < 4; ++r) {
          const float sc = acc[i][j][r];             // Q pre-scaled at proj
          const bool msk = diag && (cl > rl + r);
          P[((size_t)b*2048 + (size_t)qt*128 + rl + r) * 2048 + kt*128 + cl] =
              msk ? (_Float16)(-30000.0f) : (_Float16)sc;
        }
      }
    }
  }
}

// ---- in-place causal row softmax; one wave per row; row cached in regs ----
__global__ __launch_bounds__(256) void k_softmax(_Float16* __restrict__ P)
{
  const int lane = threadIdx.x & 63;
  const int row  = blockIdx.x * 4 + (threadIdx.x >> 6);  // 0..16383 (= b*2048+q)
  const int qIdx = row & 2047;
  _Float16* p = P + (size_t)row * 2048;
  const int L    = qIdx + 1;
  const int Lpad = ((qIdx >> 7) + 1) * 128;     // PV kernel reads up to here

  half8 xb[4];
  float m = -1e30f, s = 0.f;
  #pragma unroll
  for (int c = 0; c < 4; ++c) {
    const int i0 = lane * 8 + c * 512;
    if (i0 < Lpad) {
      half8 x = *(const half8*)(p + i0);
      xb[c] = x;
      float xv[8];
      #pragma unroll
      for (int j = 0; j < 8; ++j) xv[j] = (i0 + j < L) ? (float)x[j] : -1e30f;
      float cm = xv[0];
      #pragma unroll
      for (int j = 1; j < 8; ++j) cm = fmaxf(cm, xv[j]);
      const float mn = fmaxf(m, cm);
      float cs = 0.f;
      #pragma unroll
      for (int j = 0; j < 8; ++j) cs += __expf(xv[j] - mn);
      s = s * __expf(m - mn) + cs;
      m = mn;
    }
  }
  #pragma unroll
  for (int d = 1; d < 64; d <<= 1) {
    const float mo = __shfl_xor(m, d, 64);
    const float so = __shfl_xor(s, d, 64);
    const float mn = fmaxf(m, mo);
    s = s * __expf(m - mn) + so * __expf(mo - mn);
    m = mn;
  }
  const float inv = 1.0f / s;

  #pragma unroll
  for (int c = 0; c < 4; ++c) {
    const int i0 = lane * 8 + c * 512;
    if (i0 < Lpad) {
      half8 x = xb[c];
      half8 o;
      #pragma unroll
      for (int j = 0; j < 8; ++j)
        o[j] = (i0 + j < L) ? (_Float16)(__expf((float)x[j] - m) * inv) : (_Float16)0.f;
      *(half8*)(p + i0) = o;
    }
  }
}

// ---- out = P @ V  (B-operand = Vt[d][s]), causal K-extent ----
// 1D grid 1024: b = bid%8 (-> XCD b); r = bid/8 in [0,128): qi=r/8, dt=r%8
// (64-col output slice). 24KB LDS, (256,4) -> 4 blocks/CU, ALL 1024 resident.
// QTMAP: co-resident sets {qi, qi+4, qi+8, qi+12} have constant sum(qt)=30 ->
// every CU does identical total K-work (no causal tail).
__global__ __launch_bounds__(256, 4) void k_pv(const _Float16* __restrict__ P,
                                               const _Float16* __restrict__ Vt,
                                               float* __restrict__ Out)
{
  __shared__ __align__(16) _Float16 As[128*64], Bs[64*64];   // 24 KB
  static const int QTMAP[16] = {15,13,11,9, 0,2,4,6, 14,12,10,8, 1,3,5,7};
  const int bid = blockIdx.x;
  const int b = bid & 7;
  const int r0 = bid >> 3;
  const int qi = r0 >> 3, dt = r0 & 7;
  const int qt = QTMAP[qi];
  const int kIters = (qt + 1) * 2;

  const int tid  = threadIdx.x;
  const int lane = tid & 63;
  const int w    = tid >> 6;
  const int wm   = w >> 1, wn = w & 1;
  const int srow = tid >> 3;          // 0..31
  const int sg   = tid & 7;
  const int swz  = sg ^ (srow & 7);
  const int fr   = lane & 15;
  const int fq   = lane >> 4;
  const int fx   = lane & 7;

  const _Float16* Ap = P  + ((size_t)b*2048 + qt*128)*2048;
  const _Float16* Bv = Vt + ((size_t)b*512  + dt*64)*2048;

  f32x4 acc[4][2] = {};
  for (int it = 0; it < kIters; ++it) {
    const int k0 = it * 64;
    #pragma unroll
    for (int i = 0; i < 4; ++i)   // A: 128 rows
      gload16(Ap + (size_t)(i*32 + srow) * 2048 + (k0 + swz*8), As + i*2048 + w*512);
    #pragma unroll
    for (int i = 0; i < 2; ++i)   // B: 64 rows
      gload16(Bv + (size_t)(i*32 + srow) * 2048 + (k0 + swz*8), Bs + i*2048 + w*512);
    __syncthreads();

    #pragma unroll
    for (int ks = 0; ks < 2; ++ks) {
      half8 av[4], bv[2];
      const int slot = (ks*4 + fq) ^ fx;
      #pragma unroll
      for (int i = 0; i < 4; ++i)
        av[i] = *(const half8*)(As + (wm*64 + i*16 + fr)*64 + slot*8);
      #pragma unroll
      for (int j = 0; j < 2; ++j)
        bv[j] = *(const half8*)(Bs + (wn*32 + j*16 + fr)*64 + slot*8);
      #pragma unroll
      for (int i = 0; i < 4; ++i) {
        #pragma unroll
        for (int j = 0; j < 2; ++j)
          acc[i][j] = __builtin_amdgcn_mfma_f32_16x16x32_f16(av[i], bv[j], acc[i][j], 0, 0, 0);
      }
    }
    __syncthreads();
  }

  #pragma unroll
  for (int i = 0; i < 4; ++i) {
    const int row = qt*128 + wm*64 + i*16 + fq*4;
    #pragma unroll
    for (int j = 0; j < 2; ++j) {
      const int col = dt*64 + wn*32 + j*16 + fr;
      #pragma unroll
      for (int r = 0; r < 4; ++r)
        Out[((size_t)b*2048 + row + r) * 512 + col] = acc[i][j][r];
    }
  }
}

extern "C" void kernel_launch(void* const* d_in, const int* in_sizes, int n_in,
                              void* d_out, int out_size, void* d_ws, size_t ws_size,
                              hipStream_t stream) {
  (void)in_sizes; (void)n_in; (void)out_size;
  const float* q  = (const float*)d_in[0];
  const float* k  = (const float*)d_in[1];
  const float* v  = (const float*)d_in[2];
  // d_in[3] = causal mask: always tril per setup; implemented structurally.
  const float* Wq = (const float*)d_in[4];
  const float* bq = (const float*)d_in[5];
  const float* Wk = (const float*)d_in[6];
  const float* bk = (const float*)d_in[7];
  const float* Wv = (const float*)d_in[8];
  const float* bv = (const float*)d_in[9];

  const size_t OFF_P  = 0;
  const size_t OFF_Q  = (size_t)64 << 20;
  const size_t OFF_K  = (size_t)80 << 20;
  const size_t OFF_VT = (size_t)112 << 20;
  const size_t OFF_W  = (size_t)128 << 20;
  const size_t NEEDED = OFF_W + (size_t)3 * 512 * 512 * sizeof(_Float16);
  if (ws_size < NEEDED) return;  // diagnostic: poison-level absmax => ws too small

  char* ws = (char*)d_ws;
  _Float16* P  = (_Float16*)(ws + OFF_P);
  _Float16* Qb = (_Float16*)(ws + OFF_Q);
  _Float16* Kb = (_Float16*)(ws + OFF_K);
  _Float16* Vt = (_Float16*)(ws + OFF_VT);
  _Float16* Wb = (_Float16*)(ws + OFF_W);
  float* Out = (float*)d_out;

  k_cvtw   <<<dim3(384),  dim3(256), 0, stream>>>(Wq, Wk, Wv, Wb);
  k_proj   <<<dim3(768),  dim3(256), 0, stream>>>(q, k, v, Wb, bq, bk, bv, Qb, Kb, Vt);
  k_scores <<<dim3(576),  dim3(512), 0, stream>>>(Qb, Kb, P);
  k_softmax<<<dim3(4096), dim3(256), 0, stream>>>(P);
  k_pv     <<<dim3(1024), dim3(256), 0, stream>>>(P, Vt, Out);
}

// Round 13
// 265.683 us; speedup vs baseline: 1.0993x; 1.0993x over previous
//
// AttentionModel: fused QKV projection + causal softmax attention, MI355X/gfx950.
// Round 16: composite of confirmed winners. R15 verdict: wave-staging model
// CONFIRMED on pv (dt=8, 1024 blocks, QTMAP balance -> ~36us, -14 vs R14);
// proj regressed only because (256,3) capped VGPR at ~170 < acc[4][8]+preF
// needs -> spill (VGPR 84, WRITE_SIZE 49->128MB = scratch traffic).
//  - proj REVERTED to R12-exact: 128x256 nt2-pair tile, (256,2) (VGPR 100,
//    no spill, 64.5us measured), 66KB LDS union, single-pass V-transpose,
//    Q pre-scaled by 1/sqrt(512).
//  - pv = R15 (dt 0..7 64-col slices, grid 1024, 24KB LDS, (256,4) -> 4
//    blocks/CU all-resident; QTMAP keeps co-resident {qi,qi+4,qi+8,qi+12}
//    at constant sum(qt)=30 -> uniform per-CU K-work).
//  - scores = R14 8-wave 256x128 (statistically == R9 variant).
//  - softmax / cvtw unchanged.
// ws layout (bytes): P 0..64M | Qb 64M | Kb 80M | Vt 112M | Wf16 128M

#include <hip/hip_runtime.h>
#include <stdint.h>
#include <stddef.h>
#include <math.h>

typedef _Float16 half8 __attribute__((ext_vector_type(8)));
typedef float f32x4 __attribute__((ext_vector_type(4)));

#define SCALE_QK 0.04419417382415922f  // 1/sqrt(512)

__device__ __forceinline__ void gload16(const void* g, void* lds) {
  __builtin_amdgcn_global_load_lds(
      (const __attribute__((address_space(1))) void*)g,
      (__attribute__((address_space(3))) void*)lds,
      16, 0, 0);
}

// ---- wide K-loop (proj): C[128x256] = A[128xK](fp32) * B^T, BK=64, single-buf.
// LDS contract (proven zero-conflict): element (row r, 8-group g) at halfword
// r*64 + (g^(r&7))*8. 4 waves as 2(m) x 2(n); wave tile 64x128 -> acc[4][8].
__device__ __forceinline__ void run_kloop_wide(const float* Arow0, const _Float16* Brow0,
                                               int lda, int ldb, int kIters,
                                               _Float16* As, _Float16* Bs,
                                               f32x4 (&acc)[4][8])
{
  const int tid  = threadIdx.x;
  const int lane = tid & 63;
  const int w    = tid >> 6;
  const int wm   = w >> 1, wn = w & 1;
  const int srow = tid >> 3;          // staging row within 32-row chunk
  const int sg   = tid & 7;           // staging 8-elem group slot
  const int swz  = sg ^ (srow & 7);   // swizzled group (source side)
  const int fr   = lane & 15;
  const int fq   = lane >> 4;
  const int fx   = lane & 7;

  for (int it = 0; it < kIters; ++it) {
    const int k0 = it * 64;
    f32x4 preF[8];
    #pragma unroll
    for (int i = 0; i < 4; ++i) {
      const float* src = Arow0 + (size_t)(i*32 + srow) * lda + (k0 + sg*8);
      preF[2*i]   = *(const f32x4*)src;
      preF[2*i+1] = *(const f32x4*)(src + 4);
    }
    #pragma unroll
    for (int i = 0; i < 8; ++i)   // B: 256 rows
      gload16(Brow0 + (size_t)(i*32 + srow) * ldb + (k0 + swz*8), Bs + i*2048 + w*512);
    #pragma unroll
    for (int i = 0; i < 4; ++i) {
      f32x4 x = preF[2*i], y = preF[2*i+1];
      half8 h;
      h[0]=(_Float16)x[0]; h[1]=(_Float16)x[1]; h[2]=(_Float16)x[2]; h[3]=(_Float16)x[3];
      h[4]=(_Float16)y[0]; h[5]=(_Float16)y[1]; h[6]=(_Float16)y[2]; h[7]=(_Float16)y[3];
      *(half8*)(As + (i*32 + srow)*64 + swz*8) = h;
    }
    __syncthreads();

    #pragma unroll
    for (int ks = 0; ks < 2; ++ks) {
      half8 av[4], bv[8];
      const int slot = (ks*4 + fq) ^ fx;
      #pragma unroll
      for (int i = 0; i < 4; ++i)
        av[i] = *(const half8*)(As + (wm*64 + i*16 + fr)*64 + slot*8);
      #pragma unroll
      for (int j = 0; j < 8; ++j)
        bv[j] = *(const half8*)(Bs + (wn*128 + j*16 + fr)*64 + slot*8);
      #pragma unroll
      for (int i = 0; i < 4; ++i) {
        #pragma unroll
        for (int j = 0; j < 8; ++j)
          acc[i][j] = __builtin_amdgcn_mfma_f32_16x16x32_f16(av[i], bv[j], acc[i][j], 0, 0, 0);
      }
    }
    __syncthreads();
  }
}

// ---- weights fp32 -> f16 (3 x 512x512 concatenated) ----
__global__ __launch_bounds__(256) void k_cvtw(const float* __restrict__ Wq,
                                              const float* __restrict__ Wk,
                                              const float* __restrict__ Wv,
                                              _Float16* __restrict__ Wb)
{
  const int t = blockIdx.x * 256 + threadIdx.x;
  const int base = t * 8;
  const int z = base >> 18;
  const int off = base & 262143;
  const float* src = (z == 0) ? Wq : ((z == 1) ? Wk : Wv);
  f32x4 a = *(const f32x4*)(src + off);
  f32x4 b = *(const f32x4*)(src + off + 4);
  half8 h;
  h[0]=(_Float16)a[0]; h[1]=(_Float16)a[1]; h[2]=(_Float16)a[2]; h[3]=(_Float16)a[3];
  h[4]=(_Float16)b[0]; h[5]=(_Float16)b[1]; h[6]=(_Float16)b[2]; h[7]=(_Float16)b[3];
  *(half8*)(Wb + base) = h;
}

// ---- projections: X[16384x512](fp32) @ W^T + bias -> f16; V direct-transposed ----
// 1D grid 768: xcd = bid%8; i = bid/8 (0..95); p = xcd*48 + i/2; nt2 = i%2;
// z = p/128, mt = p%128. Block output 128 x 256 (cols nt2*256..+256).
// Q output (z==0) is PRE-SCALED by 1/sqrt(512) (bias included).
// (256,2): VGPR 100, no spill (R12-measured 64.5us; (256,3) spills -- R15).
__global__ __launch_bounds__(256, 2) void k_proj(const float* __restrict__ q,
                                                 const float* __restrict__ k,
                                                 const float* __restrict__ v,
                                                 const _Float16* __restrict__ Wb,
                                                 const float* __restrict__ bq,
                                                 const float* __restrict__ bk,
                                                 const float* __restrict__ bv,
                                                 _Float16* __restrict__ Qb,
                                                 _Float16* __restrict__ Kb,
                                                 _Float16* __restrict__ Vt)
{
  // union: {As 8192 + Bs 16384 halfs = 48KB} / V-transpose tile [256][132] = 66KB
  __shared__ __align__(16) _Float16 LDSbuf[256*132];
  _Float16* As = LDSbuf;
  _Float16* Bs = LDSbuf + 8192;

  const int bid = blockIdx.x;
  const int xcd = bid & 7, i = bid >> 3;
  const int p = xcd * 48 + (i >> 1);
  const int nt2 = i & 1;
  const int z = p >> 7, mt = p & 127;

  const float* A     = (z == 0) ? q  : (z == 1) ? k  : v;
  const float* bia   = (z == 0) ? bq : (z == 1) ? bk : bv;
  const _Float16* B  = Wb + (size_t)z * 512 * 512;

  f32x4 acc[4][8] = {};
  run_kloop_wide(A + (size_t)mt*128*512, B + (size_t)nt2*256*512, 512, 512, 8,
                 As, Bs, acc);

  const int tid = threadIdx.x;
  const int lane = tid & 63, w = tid >> 6;
  const int wm = w >> 1, wn = w & 1;
  const int fr = lane & 15, fq = lane >> 4;   // C/D: col=lane&15, row=(lane>>4)*4+reg

  if (z < 2) {
    _Float16* C = (z == 0) ? Qb : Kb;
    const float osc = (z == 0) ? SCALE_QK : 1.0f;   // pre-scale Q (and its bias)
    #pragma unroll
    for (int j = 0; j < 8; ++j) {
      const int col = nt2*256 + wn*128 + j*16 + fr;
      const float bval = bia[col];
      #pragma unroll
      for (int i2 = 0; i2 < 4; ++i2) {
        const int row = mt*128 + wm*64 + i2*16 + fq*4;
        #pragma unroll
        for (int r = 0; r < 4; ++r)
          C[(size_t)(row + r) * 512 + col] = (_Float16)((acc[i2][j][r] + bval) * osc);
      }
    }
  } else {
    // V: stage transposed tile in LDS [col 256][row 128 + pad 4], write Vt coalesced.
    _Float16* sm = LDSbuf;   // kloop ended with syncthreads: LDS free
    #pragma unroll
    for (int j = 0; j < 8; ++j) {
      const int colloc = wn*128 + j*16 + fr;          // 0..255 (d within block)
      const float bval = bia[nt2*256 + colloc];
      #pragma unroll
      for (int i2 = 0; i2 < 4; ++i2) {
        const int rowloc = wm*64 + i2*16 + fq*4;      // 0..127 (s within tile)
        #pragma unroll
        for (int r = 0; r < 4; ++r)
          sm[colloc*132 + rowloc + r] = (_Float16)(acc[i2][j][r] + bval);
      }
    }
    __syncthreads();
    const int bb = mt >> 4, s0 = (mt & 15) * 128;
    #pragma unroll
    for (int q8 = 0; q8 < 16; ++q8) {
      const int dloc = q8*16 + (tid >> 4);            // 0..255
      const int ch   = tid & 15;
      half8 o = *(const half8*)&sm[dloc*132 + ch*8];
      *(half8*)(Vt + ((size_t)bb*512 + nt2*256 + dloc)*2048 + s0 + ch*8) = o;
    }
  }
}

// ---- scores: S = (Q*scale) K^T, 8-wave 256x128 tile (R14) ----
// grid 576, 512 threads: b = bid%8 (-> XCD b); t = 71 - bid/8 (heavy-first)
// decoded to (qp, kt), kt in [0, 2qp+2). Waves 4(m) x 2(n), wave tile 64x64.
__global__ __launch_bounds__(512, 4) void k_scores(const _Float16* __restrict__ Qb,
                                                   const _Float16* __restrict__ Kb,
                                                   _Float16* __restrict__ P)
{
  __shared__ __align__(16) _Float16 As[256*64], Bs[128*64];   // 48 KB
  const int bid = blockIdx.x;
  const int b = bid & 7;
  const int t = 71 - (bid >> 3);
  int qp = 0, accum = 0;
  while (accum + 2*qp + 2 <= t) { accum += 2*qp + 2; ++qp; }
  const int kt = t - accum;          // 0 .. 2qp+1
  const int qt0 = 2 * qp;

  const int tid  = threadIdx.x;
  const int lane = tid & 63;
  const int w    = tid >> 6;         // 0..7
  const int wm   = w >> 1, wn = w & 1;
  const int srow = tid >> 3;         // 0..63 (staging row within 64-row chunk)
  const int sg   = tid & 7;
  const int swz  = sg ^ (srow & 7);
  const int fr   = lane & 15;
  const int fq   = lane >> 4;
  const int fx   = lane & 7;

  const _Float16* Aq = Qb + ((size_t)b*2048 + (size_t)qt0*128)*512;
  const _Float16* Bk = Kb + ((size_t)b*2048 + (size_t)kt*128)*512;

  f32x4 acc[4][4] = {};
  for (int it = 0; it < 8; ++it) {
    const int k0 = it * 64;
    #pragma unroll
    for (int i = 0; i < 4; ++i)   // A: 256 rows (4 x 64-row passes)
      gload16(Aq + (size_t)(i*64 + srow) * 512 + (k0 + swz*8), As + i*4096 + w*512);
    #pragma unroll
    for (int i = 0; i < 2; ++i)   // B: 128 rows (2 x 64-row passes)
      gload16(Bk + (size_t)(i*64 + srow) * 512 + (k0 + swz*8), Bs + i*4096 + w*512);
    __syncthreads();

    #pragma unroll
    for (int ks = 0; ks < 2; ++ks) {
      half8 av[4], bv[4];
      const int slot = (ks*4 + fq) ^ fx;
      #pragma unroll
      for (int i = 0; i < 4; ++i) {
        av[i] = *(const half8*)(As + (wm*64 + i*16 + fr)*64 + slot*8);
        bv[i] = *(const half8*)(Bs + (wn*64 + i*16 + fr)*64 + slot*8);
      }
      #pragma unroll
      for (int i = 0; i < 4; ++i) {
        #pragma unroll
        for (int j = 0; j < 4; ++j)
          acc[i][j] = __builtin_amdgcn_mfma_f32_16x16x32_f16(av[i], bv[j], acc[i][j], 0, 0, 0);
      }
    }
    __syncthreads();
  }

  // epilogue: wave's rows live in qt tile qt0 + (wm>>1)
  const int qt = qt0 + (wm >> 1);
  if (kt <= qt) {
    const bool diag = (kt == qt);
    #pragma unroll
    for (int i = 0; i < 4; ++i) {
      const int rl = (wm & 1)*64 + i*16 + fq*4;      // row within the qt tile
      #pragma unroll
      for (int j = 0; j < 4; ++j) {
        const int cl = wn*64 + j*16 + fr;            // col within kt tile
        #pragma unroll
        for (int r = 0; r < 4; ++r) {
          const float sc = acc[i][j][r];             // Q pre-scaled at proj
          const bool msk = diag && (cl > rl + r);
          P[((size_t)b*2048 + (size_t)qt*128 + rl + r) * 2048 + kt*128 + cl] =
              msk ? (_Float16)(-30000.0f) : (_Float16)sc;
        }
      }
    }
  }
}

// ---- in-place causal row softmax; one wave per row; row cached in regs ----
__global__ __launch_bounds__(256) void k_softmax(_Float16* __restrict__ P)
{
  const int lane = threadIdx.x & 63;
  const int row  = blockIdx.x * 4 + (threadIdx.x >> 6);  // 0..16383 (= b*2048+q)
  const int qIdx = row & 2047;
  _Float16* p = P + (size_t)row * 2048;
  const int L    = qIdx + 1;
  const int Lpad = ((qIdx >> 7) + 1) * 128;     // PV kernel reads up to here

  half8 xb[4];
  float m = -1e30f, s = 0.f;
  #pragma unroll
  for (int c = 0; c < 4; ++c) {
    const int i0 = lane * 8 + c * 512;
    if (i0 < Lpad) {
      half8 x = *(const half8*)(p + i0);
      xb[c] = x;
      float xv[8];
      #pragma unroll
      for (int j = 0; j < 8; ++j) xv[j] = (i0 + j < L) ? (float)x[j] : -1e30f;
      float cm = xv[0];
      #pragma unroll
      for (int j = 1; j < 8; ++j) cm = fmaxf(cm, xv[j]);
      const float mn = fmaxf(m, cm);
      float cs = 0.f;
      #pragma unroll
      for (int j = 0; j < 8; ++j) cs += __expf(xv[j] - mn);
      s = s * __expf(m - mn) + cs;
      m = mn;
    }
  }
  #pragma unroll
  for (int d = 1; d < 64; d <<= 1) {
    const float mo = __shfl_xor(m, d, 64);
    const float so = __shfl_xor(s, d, 64);
    const float mn = fmaxf(m, mo);
    s = s * __expf(m - mn) + so * __expf(mo - mn);
    m = mn;
  }
  const float inv = 1.0f / s;

  #pragma unroll
  for (int c = 0; c < 4; ++c) {
    const int i0 = lane * 8 + c * 512;
    if (i0 < Lpad) {
      half8 x = xb[c];
      half8 o;
      #pragma unroll
      for (int j = 0; j < 8; ++j)
        o[j] = (i0 + j < L) ? (_Float16)(__expf((float)x[j] - m) * inv) : (_Float16)0.f;
      *(half8*)(p + i0) = o;
    }
  }
}

// ---- out = P @ V  (B-operand = Vt[d][s]), causal K-extent ----
// 1D grid 1024: b = bid%8 (-> XCD b); r = bid/8 in [0,128): qi=r/8, dt=r%8
// (64-col output slice). 24KB LDS, (256,4) -> 4 blocks/CU, ALL 1024 resident.
// QTMAP: co-resident sets {qi, qi+4, qi+8, qi+12} have constant sum(qt)=30 ->
// every CU does identical total K-work (no causal tail). [R15: confirmed ~-14us]
__global__ __launch_bounds__(256, 4) void k_pv(const _Float16* __restrict__ P,
                                               const _Float16* __restrict__ Vt,
                                               float* __restrict__ Out)
{
  __shared__ __align__(16) _Float16 As[128*64], Bs[64*64];   // 24 KB
  static const int QTMAP[16] = {15,13,11,9, 0,2,4,6, 14,12,10,8, 1,3,5,7};
  const int bid = blockIdx.x;
  const int b = bid & 7;
  const int r0 = bid >> 3;
  const int qi = r0 >> 3, dt = r0 & 7;
  const int qt = QTMAP[qi];
  const int kIters = (qt + 1) * 2;

  const int tid  = threadIdx.x;
  const int lane = tid & 63;
  const int w    = tid >> 6;
  const int wm   = w >> 1, wn = w & 1;
  const int srow = tid >> 3;          // 0..31
  const int sg   = tid & 7;
  const int swz  = sg ^ (srow & 7);
  const int fr   = lane & 15;
  const int fq   = lane >> 4;
  const int fx   = lane & 7;

  const _Float16* Ap = P  + ((size_t)b*2048 + qt*128)*2048;
  const _Float16* Bv = Vt + ((size_t)b*512  + dt*64)*2048;

  f32x4 acc[4][2] = {};
  for (int it = 0; it < kIters; ++it) {
    const int k0 = it * 64;
    #pragma unroll
    for (int i = 0; i < 4; ++i)   // A: 128 rows
      gload16(Ap + (size_t)(i*32 + srow) * 2048 + (k0 + swz*8), As + i*2048 + w*512);
    #pragma unroll
    for (int i = 0; i < 2; ++i)   // B: 64 rows
      gload16(Bv + (size_t)(i*32 + srow) * 2048 + (k0 + swz*8), Bs + i*2048 + w*512);
    __syncthreads();

    #pragma unroll
    for (int ks = 0; ks < 2; ++ks) {
      half8 av[4], bv[2];
      const int slot = (ks*4 + fq) ^ fx;
      #pragma unroll
      for (int i = 0; i < 4; ++i)
        av[i] = *(const half8*)(As + (wm*64 + i*16 + fr)*64 + slot*8);
      #pragma unroll
      for (int j = 0; j < 2; ++j)
        bv[j] = *(const half8*)(Bs + (wn*32 + j*16 + fr)*64 + slot*8);
      #pragma unroll
      for (int i = 0; i < 4; ++i) {
        #pragma unroll
        for (int j = 0; j < 2; ++j)
          acc[i][j] = __builtin_amdgcn_mfma_f32_16x16x32_f16(av[i], bv[j], acc[i][j], 0, 0, 0);
      }
    }
    __syncthreads();
  }

  #pragma unroll
  for (int i = 0; i < 4; ++i) {
    const int row = qt*128 + wm*64 + i*16 + fq*4;
    #pragma unroll
    for (int j = 0; j < 2; ++j) {
      const int col = dt*64 + wn*32 + j*16 + fr;
      #pragma unroll
      for (int r = 0; r < 4; ++r)
        Out[((size_t)b*2048 + row + r) * 512 + col] = acc[i][j][r];
    }
  }
}

extern "C" void kernel_launch(void* const* d_in, const int* in_sizes, int n_in,
                              void* d_out, int out_size, void* d_ws, size_t ws_size,
                              hipStream_t stream) {
  (void)in_sizes; (void)n_in; (void)out_size;
  const float* q  = (const float*)d_in[0];
  const float* k  = (const float*)d_in[1];
  const float* v  = (const float*)d_in[2];
  // d_in[3] = causal mask: always tril per setup; implemented structurally.
  const float* Wq = (const float*)d_in[4];
  const float* bq = (const float*)d_in[5];
  const float* Wk = (const float*)d_in[6];
  const float* bk = (const float*)d_in[7];
  const float* Wv = (const float*)d_in[8];
  const float* bv = (const float*)d_in[9];

  const size_t OFF_P  = 0;
  const size_t OFF_Q  = (size_t)64 << 20;
  const size_t OFF_K  = (size_t)80 << 20;
  const size_t OFF_VT = (size_t)112 << 20;
  const size_t OFF_W  = (size_t)128 << 20;
  const size_t NEEDED = OFF_W + (size_t)3 * 512 * 512 * sizeof(_Float16);
  if (ws_size < NEEDED) return;  // diagnostic: poison-level absmax => ws too small

  char* ws = (char*)d_ws;
  _Float16* P  = (_Float16*)(ws + OFF_P);
  _Float16* Qb = (_Float16*)(ws + OFF_Q);
  _Float16* Kb = (_Float16*)(ws + OFF_K);
  _Float16* Vt = (_Float16*)(ws + OFF_VT);
  _Float16* Wb = (_Float16*)(ws + OFF_W);
  float* Out = (float*)d_out;

  k_cvtw   <<<dim3(384),  dim3(256), 0, stream>>>(Wq, Wk, Wv, Wb);
  k_proj   <<<dim3(768),  dim3(256), 0, stream>>>(q, k, v, Wb, bq, bk, bv, Qb, Kb, Vt);
  k_scores <<<dim3(576),  dim3(512), 0, stream>>>(Qb, Kb, P);
  k_softmax<<<dim3(4096), dim3(256), 0, stream>>>(P);
  k_pv     <<<dim3(1024), dim3(256), 0, stream>>>(P, Vt, Out);
}